// Round 5
// baseline (116.679 us; speedup 1.0000x reference)
//
#include <hip/hip_runtime.h>

// 2x upsample with binomial blur [1,4,6,4,1]/8 per axis, edge clamp.
// Per-axis closed form (clamp c() to [0,47]):
//   y[2a]   = (x[c(a-1)] + 6*x[a] + x[c(a+1)]) / 8
//   y[2a+1] = (x[a] + x[c(a+1)]) / 2
// Each thread: 2x2x4-input block -> 4x4x8 output block (128 floats).
// Per neighbor row: one aligned float4 + 2 clamped scalars (vs 2x{float2+2
// scalars}) -> per-output VMEM instruction count halved on both sides.
// All /8,/2 scaling deferred to one exact power-of-two multiply per output.

typedef float f32x4 __attribute__((ext_vector_type(4)));

constexpr int DIN = 48, HIN = 48, WIN = 48;
constexpr int HW = HIN * WIN;          // 2304
constexpr int HOUT = 96, WOUT = 96;
constexpr int PS = HOUT * WOUT;        // output d-plane stride, 9216
constexpr int NC = 64;
constexpr int THREADS = NC * 24 * 24 * 12;  // 442368

__global__ __launch_bounds__(256) void Upsample2x2x2_kernel(
    const float* __restrict__ x, float* __restrict__ out)
{
    int idx = blockIdx.x * 256 + threadIdx.x;
    int t   = idx % 12;        // input w 4t..4t+3, outputs w 8t..8t+7
    int tmp = idx / 12;
    int b0h = tmp % 24;
    tmp    /= 24;
    int a0h = tmp % 24;
    int nc  = tmp / 24;

    const int a0 = a0h * 2, b0 = b0h * 2, w0 = t * 4;
    const float* __restrict__ xb = x + nc * (DIN * HW);

    const int ai[4] = { a0 > 0 ? a0 - 1 : 0, a0, a0 + 1,
                        a0 + 2 < DIN ? a0 + 2 : DIN - 1 };
    const int bi[4] = { b0 > 0 ? b0 - 1 : 0, b0, b0 + 1,
                        b0 + 2 < HIN ? b0 + 2 : HIN - 1 };
    const int wm = w0 > 0 ? w0 - 1 : 0;
    const int wp = w0 + 4 < WIN ? w0 + 4 : WIN - 1;

    float* __restrict__ ob = out + nc * (2 * DIN * PS);
    const int obase = (a0 * 2 * HOUT + b0 * 2) * WOUT + t * 8;

    // rolling H-combined state per d-neighbor i, per h-output-pair win
    float He[4][2][8], Ho[4][2][8];

    #pragma unroll
    for (int i = 0; i < 4; i++) {
        const float* __restrict__ xd = xb + ai[i] * HW;

        // W-stage for the 4 h-neighbor rows of this d: 8 unscaled values
        // [E(w),O(w)] alternating for w = 4t..4t+3
        float rr[4][8];
        #pragma unroll
        for (int j = 0; j < 4; j++) {
            const float* __restrict__ row = xd + bi[j] * WIN;
            f32x4 m = *reinterpret_cast<const f32x4*>(row + w0);  // 16B aligned
            float u0 = row[wm];
            float u5 = row[wp];
            rr[j][0] = fmaf(6.f, m.x, u0)  + m.y;
            rr[j][1] = m.x + m.y;
            rr[j][2] = fmaf(6.f, m.y, m.x) + m.z;
            rr[j][3] = m.y + m.z;
            rr[j][4] = fmaf(6.f, m.z, m.y) + m.w;
            rr[j][5] = m.z + m.w;
            rr[j][6] = fmaf(6.f, m.w, m.z) + u5;
            rr[j][7] = m.w + u5;
        }

        // H-stage
        #pragma unroll
        for (int win = 0; win < 2; win++)
            #pragma unroll
            for (int k = 0; k < 8; k++) {
                He[i][win][k] = fmaf(6.f, rr[win + 1][k], rr[win][k]) + rr[win + 2][k];
                Ho[i][win][k] = rr[win + 1][k] + rr[win + 2][k];
            }

        // D-stage + store as soon as a window of 3 d-rows is complete
        if (i >= 2) {
            const int ap = i - 2;   // output d-pair 2(a0+ap), +1
            #pragma unroll
            for (int win = 0; win < 2; win++) {
                float vee[8], voe[8], veo[8], voo[8];
                #pragma unroll
                for (int k = 0; k < 8; k++) {
                    vee[k] = fmaf(6.f, He[ap + 1][win][k], He[ap][win][k]) + He[ap + 2][win][k];
                    voe[k] = He[ap + 1][win][k] + He[ap + 2][win][k];
                    veo[k] = fmaf(6.f, Ho[ap + 1][win][k], Ho[ap][win][k]) + Ho[ap + 2][win][k];
                    voo[k] = Ho[ap + 1][win][k] + Ho[ap + 2][win][k];
                }
                const int rbase = obase + ap * 2 * PS + win * 2 * WOUT;
                // scales: per-axis even=1/8, odd=1/2; w-parity alternates in lane
                f32x4 s0a = { vee[0] * (1.f/512), vee[1] * (1.f/128),
                              vee[2] * (1.f/512), vee[3] * (1.f/128) };
                f32x4 s0b = { vee[4] * (1.f/512), vee[5] * (1.f/128),
                              vee[6] * (1.f/512), vee[7] * (1.f/128) };
                f32x4 s1a = { veo[0] * (1.f/128), veo[1] * (1.f/32),
                              veo[2] * (1.f/128), veo[3] * (1.f/32) };
                f32x4 s1b = { veo[4] * (1.f/128), veo[5] * (1.f/32),
                              veo[6] * (1.f/128), veo[7] * (1.f/32) };
                f32x4 s2a = { voe[0] * (1.f/128), voe[1] * (1.f/32),
                              voe[2] * (1.f/128), voe[3] * (1.f/32) };
                f32x4 s2b = { voe[4] * (1.f/128), voe[5] * (1.f/32),
                              voe[6] * (1.f/128), voe[7] * (1.f/32) };
                f32x4 s3a = { voo[0] * (1.f/32),  voo[1] * (1.f/8),
                              voo[2] * (1.f/32),  voo[3] * (1.f/8) };
                f32x4 s3b = { voo[4] * (1.f/32),  voo[5] * (1.f/8),
                              voo[6] * (1.f/32),  voo[7] * (1.f/8) };
                __builtin_nontemporal_store(s0a, reinterpret_cast<f32x4*>(ob + rbase));
                __builtin_nontemporal_store(s0b, reinterpret_cast<f32x4*>(ob + rbase + 4));
                __builtin_nontemporal_store(s1a, reinterpret_cast<f32x4*>(ob + rbase + WOUT));
                __builtin_nontemporal_store(s1b, reinterpret_cast<f32x4*>(ob + rbase + WOUT + 4));
                __builtin_nontemporal_store(s2a, reinterpret_cast<f32x4*>(ob + rbase + PS));
                __builtin_nontemporal_store(s2b, reinterpret_cast<f32x4*>(ob + rbase + PS + 4));
                __builtin_nontemporal_store(s3a, reinterpret_cast<f32x4*>(ob + rbase + PS + WOUT));
                __builtin_nontemporal_store(s3b, reinterpret_cast<f32x4*>(ob + rbase + PS + WOUT + 4));
            }
        }
    }
}

extern "C" void kernel_launch(void* const* d_in, const int* in_sizes, int n_in,
                              void* d_out, int out_size, void* d_ws, size_t ws_size,
                              hipStream_t stream) {
    const float* x = (const float*)d_in[0];
    float* out = (float*)d_out;
    int blocks = THREADS / 256;  // 1728, exact
    Upsample2x2x2_kernel<<<blocks, 256, 0, stream>>>(x, out);
}

// Round 6
// 50.152 us; speedup vs baseline: 2.3265x; 2.3265x over previous
//
#include <hip/hip_runtime.h>

// 2x upsample with binomial blur [1,4,6,4,1]/8 per axis, edge clamp.
// Per-axis closed form (clamp c() to [0,47]):
//   y[2a]   = (x[c(a-1)] + 6*x[a] + x[c(a+1)]) / 8
//   y[2a+1] = (x[a] + x[c(a+1)]) / 2
// Each thread: 2x2x2-input block -> 4x4x4 output block (64 floats).
// Round-3 structure (best: 47.8us), A/B change: plain f32x4 stores instead of
// __builtin_nontemporal_store (the 7TB/s fill kernels use plain stores).
// All /8,/2 scaling deferred to one exact power-of-two multiply per output.

typedef float f32x4 __attribute__((ext_vector_type(4)));

constexpr int DIN = 48, HIN = 48, WIN = 48;
constexpr int HW = HIN * WIN;          // 2304
constexpr int HOUT = 96, WOUT = 96;
constexpr int PS = HOUT * WOUT;        // output d-plane stride, 9216
constexpr int NC = 64;
constexpr int THREADS = NC * 24 * 24 * 24;  // 884736

__global__ __launch_bounds__(256) void Upsample2x2x2_kernel(
    const float* __restrict__ x, float* __restrict__ out)
{
    int idx = blockIdx.x * 256 + threadIdx.x;
    int t   = idx % 24;        // input w0 = 2t, outputs w 4t..4t+3
    int tmp = idx / 24;
    int b0h = tmp % 24;
    tmp    /= 24;
    int a0h = tmp % 24;
    int nc  = tmp / 24;

    const int a0 = a0h * 2, b0 = b0h * 2, w0 = t * 2;
    const float* __restrict__ xb = x + nc * (DIN * HW);

    const int ai[4] = { a0 > 0 ? a0 - 1 : 0, a0, a0 + 1,
                        a0 + 2 < DIN ? a0 + 2 : DIN - 1 };
    const int bi[4] = { b0 > 0 ? b0 - 1 : 0, b0, b0 + 1,
                        b0 + 2 < HIN ? b0 + 2 : HIN - 1 };
    const int wm = w0 > 0 ? w0 - 1 : 0;
    const int wp = w0 + 2 < WIN ? w0 + 2 : WIN - 1;

    // W-stage (unscaled): per neighbor row, 4 values
    // k0 = E(w0) = u0+6u1+u2 ; k1 = O(w0) = u1+u2
    // k2 = E(w0+1) = u1+6u2+u3 ; k3 = O(w0+1) = u2+u3
    float r[4][4][4];
    #pragma unroll
    for (int i = 0; i < 4; i++) {
        const float* __restrict__ xd = xb + ai[i] * HW;
        #pragma unroll
        for (int j = 0; j < 4; j++) {
            const float* __restrict__ row = xd + bi[j] * WIN;
            float2 m = *reinterpret_cast<const float2*>(row + w0);  // 8B aligned
            float u0 = row[wm];
            float u3 = row[wp];
            float u1 = m.x, u2 = m.y;
            r[i][j][0] = fmaf(6.f, u1, u0) + u2;
            r[i][j][1] = u1 + u2;
            r[i][j][2] = fmaf(6.f, u2, u1) + u3;
            r[i][j][3] = u2 + u3;
        }
    }

    float* __restrict__ ob = out + nc * (2 * DIN * PS);
    const int obase = (a0 * 2 * HOUT + b0 * 2) * WOUT + t * 4;

    #pragma unroll
    for (int win = 0; win < 2; win++) {   // h output pair 2(b0+win), +1
        float He[4][4], Ho[4][4];         // H-combined, per d-row, unscaled
        #pragma unroll
        for (int i = 0; i < 4; i++)
            #pragma unroll
            for (int k = 0; k < 4; k++) {
                He[i][k] = fmaf(6.f, r[i][win + 1][k], r[i][win][k]) + r[i][win + 2][k];
                Ho[i][k] = r[i][win + 1][k] + r[i][win + 2][k];
            }

        #pragma unroll
        for (int ap = 0; ap < 2; ap++) {  // d output pair 2(a0+ap), +1
            float vee[4], voe[4], veo[4], voo[4];
            #pragma unroll
            for (int k = 0; k < 4; k++) {
                vee[k] = fmaf(6.f, He[ap + 1][k], He[ap][k]) + He[ap + 2][k];
                voe[k] = He[ap + 1][k] + He[ap + 2][k];
                veo[k] = fmaf(6.f, Ho[ap + 1][k], Ho[ap][k]) + Ho[ap + 2][k];
                voo[k] = Ho[ap + 1][k] + Ho[ap + 2][k];
            }
            const int rbase = obase + ap * 2 * PS + win * 2 * WOUT;
            // scales: per-axis even=1/8, odd=1/2; w-parity alternates in lane
            f32x4 s0 = { vee[0] * (1.f/512), vee[1] * (1.f/128),
                         vee[2] * (1.f/512), vee[3] * (1.f/128) };
            f32x4 s1 = { veo[0] * (1.f/128), veo[1] * (1.f/32),
                         veo[2] * (1.f/128), veo[3] * (1.f/32) };
            f32x4 s2 = { voe[0] * (1.f/128), voe[1] * (1.f/32),
                         voe[2] * (1.f/128), voe[3] * (1.f/32) };
            f32x4 s3 = { voo[0] * (1.f/32),  voo[1] * (1.f/8),
                         voo[2] * (1.f/32),  voo[3] * (1.f/8) };
            *reinterpret_cast<f32x4*>(ob + rbase)              = s0;
            *reinterpret_cast<f32x4*>(ob + rbase + WOUT)       = s1;
            *reinterpret_cast<f32x4*>(ob + rbase + PS)         = s2;
            *reinterpret_cast<f32x4*>(ob + rbase + PS + WOUT)  = s3;
        }
    }
}

extern "C" void kernel_launch(void* const* d_in, const int* in_sizes, int n_in,
                              void* d_out, int out_size, void* d_ws, size_t ws_size,
                              hipStream_t stream) {
    const float* x = (const float*)d_in[0];
    float* out = (float*)d_out;
    int blocks = THREADS / 256;  // 3456, exact
    Upsample2x2x2_kernel<<<blocks, 256, 0, stream>>>(x, out);
}

// Round 7
// 48.851 us; speedup vs baseline: 2.3885x; 1.0266x over previous
//
#include <hip/hip_runtime.h>

// 2x upsample with binomial blur [1,4,6,4,1]/8 per axis, edge clamp.
// Per-axis closed form (clamp c() to [0,47]):
//   y[2a]   = (x[c(a-1)] + 6*x[a] + x[c(a+1)]) / 8
//   y[2a+1] = (x[a] + x[c(a+1)]) / 2
// Each thread: 2x2x2-input block -> 4x4x4 output block (64 floats).
// Round-3 structure + nt stores (proven best). This round: single 16B
// dword-aligned load per neighbor row (was float2 + 2 scalars), covering
// w0-1..w0+2 with an edge shift and cndmask selects -> VMEM instrs/thread
// 64 -> 32. u-values bit-identical to before.
// All /8,/2 scaling deferred to one exact power-of-two multiply per output.

typedef float f32x4 __attribute__((ext_vector_type(4)));

constexpr int DIN = 48, HIN = 48, WIN = 48;
constexpr int HW = HIN * WIN;          // 2304
constexpr int HOUT = 96, WOUT = 96;
constexpr int PS = HOUT * WOUT;        // output d-plane stride, 9216
constexpr int NC = 64;
constexpr int THREADS = NC * 24 * 24 * 24;  // 884736

__global__ __launch_bounds__(256) void Upsample2x2x2_kernel(
    const float* __restrict__ x, float* __restrict__ out)
{
    int idx = blockIdx.x * 256 + threadIdx.x;
    int t   = idx % 24;        // input w0 = 2t, outputs w 4t..4t+3
    int tmp = idx / 24;
    int b0h = tmp % 24;
    tmp    /= 24;
    int a0h = tmp % 24;
    int nc  = tmp / 24;

    const int a0 = a0h * 2, b0 = b0h * 2, w0 = t * 2;
    const float* __restrict__ xb = x + nc * (DIN * HW);

    const int ai[4] = { a0 > 0 ? a0 - 1 : 0, a0, a0 + 1,
                        a0 + 2 < DIN ? a0 + 2 : DIN - 1 };
    const int bi[4] = { b0 > 0 ? b0 - 1 : 0, b0, b0 + 1,
                        b0 + 2 < HIN ? b0 + 2 : HIN - 1 };

    // One 16B load per row at w0+shift; selects map lanes to u0..u3.
    // interior (1<=t<=22): shift=-1, v = [w0-1, w0, w0+1, w0+2]
    // t==0:  shift= 0, v = [0,1,2,3];  u0=u1=v.x? no: u0=v.x,u1=v.x,u2=v.y,u3=v.z
    // t==23: shift=-2, v = [44,45,46,47]; u0=v.y,u1=v.z,u2=v.w,u3=v.w
    const bool lo = (t == 0), hi = (t == 23);
    const int base = w0 + (lo ? 0 : (hi ? -2 : -1));

    // W-stage (unscaled): per neighbor row, 4 values
    // k0 = E(w0) = u0+6u1+u2 ; k1 = O(w0) = u1+u2
    // k2 = E(w0+1) = u1+6u2+u3 ; k3 = O(w0+1) = u2+u3
    float r[4][4][4];
    #pragma unroll
    for (int i = 0; i < 4; i++) {
        const float* __restrict__ xd = xb + ai[i] * HW;
        #pragma unroll
        for (int j = 0; j < 4; j++) {
            const float* __restrict__ row = xd + bi[j] * WIN;
            f32x4 v;
            __builtin_memcpy(&v, __builtin_assume_aligned(row + base, 4), 16);
            float u0 = hi ? v.y : v.x;
            float u1 = lo ? v.x : (hi ? v.z : v.y);
            float u2 = lo ? v.y : (hi ? v.w : v.z);
            float u3 = lo ? v.z : v.w;
            r[i][j][0] = fmaf(6.f, u1, u0) + u2;
            r[i][j][1] = u1 + u2;
            r[i][j][2] = fmaf(6.f, u2, u1) + u3;
            r[i][j][3] = u2 + u3;
        }
    }

    float* __restrict__ ob = out + nc * (2 * DIN * PS);
    const int obase = (a0 * 2 * HOUT + b0 * 2) * WOUT + t * 4;

    #pragma unroll
    for (int win = 0; win < 2; win++) {   // h output pair 2(b0+win), +1
        float He[4][4], Ho[4][4];         // H-combined, per d-row, unscaled
        #pragma unroll
        for (int i = 0; i < 4; i++)
            #pragma unroll
            for (int k = 0; k < 4; k++) {
                He[i][k] = fmaf(6.f, r[i][win + 1][k], r[i][win][k]) + r[i][win + 2][k];
                Ho[i][k] = r[i][win + 1][k] + r[i][win + 2][k];
            }

        #pragma unroll
        for (int ap = 0; ap < 2; ap++) {  // d output pair 2(a0+ap), +1
            float vee[4], voe[4], veo[4], voo[4];
            #pragma unroll
            for (int k = 0; k < 4; k++) {
                vee[k] = fmaf(6.f, He[ap + 1][k], He[ap][k]) + He[ap + 2][k];
                voe[k] = He[ap + 1][k] + He[ap + 2][k];
                veo[k] = fmaf(6.f, Ho[ap + 1][k], Ho[ap][k]) + Ho[ap + 2][k];
                voo[k] = Ho[ap + 1][k] + Ho[ap + 2][k];
            }
            const int rbase = obase + ap * 2 * PS + win * 2 * WOUT;
            // scales: per-axis even=1/8, odd=1/2; w-parity alternates in lane
            f32x4 s0 = { vee[0] * (1.f/512), vee[1] * (1.f/128),
                         vee[2] * (1.f/512), vee[3] * (1.f/128) };
            f32x4 s1 = { veo[0] * (1.f/128), veo[1] * (1.f/32),
                         veo[2] * (1.f/128), veo[3] * (1.f/32) };
            f32x4 s2 = { voe[0] * (1.f/128), voe[1] * (1.f/32),
                         voe[2] * (1.f/128), voe[3] * (1.f/32) };
            f32x4 s3 = { voo[0] * (1.f/32),  voo[1] * (1.f/8),
                         voo[2] * (1.f/32),  voo[3] * (1.f/8) };
            __builtin_nontemporal_store(s0, reinterpret_cast<f32x4*>(ob + rbase));
            __builtin_nontemporal_store(s1, reinterpret_cast<f32x4*>(ob + rbase + WOUT));
            __builtin_nontemporal_store(s2, reinterpret_cast<f32x4*>(ob + rbase + PS));
            __builtin_nontemporal_store(s3, reinterpret_cast<f32x4*>(ob + rbase + PS + WOUT));
        }
    }
}

extern "C" void kernel_launch(void* const* d_in, const int* in_sizes, int n_in,
                              void* d_out, int out_size, void* d_ws, size_t ws_size,
                              hipStream_t stream) {
    const float* x = (const float*)d_in[0];
    float* out = (float*)d_out;
    int blocks = THREADS / 256;  // 3456, exact
    Upsample2x2x2_kernel<<<blocks, 256, 0, stream>>>(x, out);
}